// Round 24
// baseline (240.892 us; speedup 1.0000x reference)
//
#include <hip/hip_runtime.h>
#include <hip/hip_bf16.h>
#include <stdint.h>

#define B_ 2
#define T_ 2048
#define C_ 2048
#define NH 16
#define NKV 4
#define HD 128

typedef __attribute__((ext_vector_type(4))) float f32x4;
typedef __attribute__((ext_vector_type(8))) short bf16x8;
typedef __attribute__((ext_vector_type(4))) int i32x4;

static __device__ __forceinline__ ushort f2bf(float f) {
  return __bfloat16_as_ushort(__float2bfloat16(f));
}
static __device__ __forceinline__ uint32_t pack_bf(float a, float b) {
  return (uint32_t)f2bf(a) | ((uint32_t)f2bf(b) << 16);
}

typedef __attribute__((address_space(1))) const void g1void;
typedef __attribute__((address_space(3))) void l3void;
static __device__ __forceinline__ void gload16(const void* g, void* l) {
  // async global->LDS, 16B per lane; LDS dest = wave-uniform base + lane*16
  __builtin_amdgcn_global_load_lds((g1void*)g, (l3void*)l, 16, 0, 0);
}

// ---- all f32 -> bf16 casts in ONE dispatch (segmented grid) ----
// segments: x (1024 blocks), wq (512), wkv (256), wo (512) = 2304 blocks.
__global__ __launch_bounds__(256)
void cast_all(const float* __restrict__ x, const float* __restrict__ wq,
              const float* __restrict__ wkv, const float* __restrict__ wo,
              ushort* __restrict__ xb, ushort* __restrict__ wqkvb,
              ushort* __restrict__ wob) {
  const int bid = blockIdx.x;
  const float* src; ushort* dst; int n4, b0, nblk;
  if (bid < 1024)      { src = x;   dst = xb;    n4 = 2097152; b0 = 0;    nblk = 1024; }
  else if (bid < 1536) { src = wq;  dst = wqkvb; n4 = 1048576; b0 = 1024; nblk = 512; }
  else if (bid < 1792) { src = wkv; dst = wqkvb + (size_t)2048 * 2048;
                         n4 = 524288;  b0 = 1536; nblk = 256; }
  else                 { src = wo;  dst = wob;   n4 = 1048576; b0 = 1792; nblk = 512; }
  for (int i = (bid - b0) * 256 + threadIdx.x; i < n4; i += nblk * 256) {
    float4 v = ((const float4*)src)[i];
    ushort4 o;
    o.x = f2bf(v.x); o.y = f2bf(v.y); o.z = f2bf(v.z); o.w = f2bf(v.w);
    ((ushort4*)dst)[i] = o;
  }
}

// ---- bf16 MFMA GEMM: 128x64 tile for BOTH modes (r19: BN=32 regressed;
// BN=64 is the measured local optimum). 256 thr = 4 waves (2x2), wave 64x32
// (acc 4x2). 1-phase (r10: explicit dbuf loses cross-block TLP per m114).
// MODE 0: C = A@W^T + bias, f32 out (O-projection).
// MODE 3: combined QKV projection, N=3072 (W = [wq; wkv] stacked):
//   cn < 2048: RoPE*scale -> Qb;  cn < 2560: RoPE -> Kb;
//   else: transpose-store -> Vt[b][g][d][t] (r=0..3 = 4 consecutive t).
// Region branch block-uniform (boundaries multiples of 64).
// RoPE pair element via __shfl_xor(v,1): lane parity == column parity.
template<int MODE, int BN>
__global__ __launch_bounds__(256)
void gemm_mfma(const ushort* __restrict__ A, const ushort* __restrict__ W,
               const float* __restrict__ bias, float* __restrict__ Cf,
               ushort* __restrict__ O1, ushort* __restrict__ O2,
               ushort* __restrict__ O3,
               const float* __restrict__ rf, int M, int N, int K) {
  constexpr int NJ = BN / 32;
  __shared__ __align__(16) ushort As[128 * 64];
  __shared__ __align__(16) ushort Ws[BN * 64];
  const int tid = threadIdx.x;
  const int lane = tid & 63, wid = tid >> 6;
  const int wr = wid >> 1, wc = wid & 1;       // wave grid 2x2 (rows 64, cols BN/2)
  const int lr = lane & 15, lg = lane >> 4;
  const int bm = blockIdx.y * 128, bn = blockIdx.x * BN;

  f32x4 acc[4][NJ];
  #pragma unroll
  for (int mi = 0; mi < 4; ++mi)
    #pragma unroll
    for (int nj = 0; nj < NJ; ++nj) acc[mi][nj] = f32x4{0.f, 0.f, 0.f, 0.f};

  const ushort* Ab = A + (size_t)bm * K;
  const ushort* Wb = W + (size_t)bn * K;

  for (int k0 = 0; k0 < K; k0 += 64) {
    // stage A 128x64 (1024 x 16B chunks), W BNx64 (BN*8 chunks)
    #pragma unroll
    for (int it = 0; it < 4; ++it) {
      const int cid = it * 256 + tid;
      const int r = cid >> 3, cc = (cid & 7) * 8;
      gload16(Ab + (size_t)r * K + k0 + cc, &As[cid * 8]);
    }
    #pragma unroll
    for (int it = 0; it < NJ; ++it) {
      const int cid = it * 256 + tid;
      const int r = cid >> 3, cc = (cid & 7) * 8;
      gload16(Wb + (size_t)r * K + k0 + cc, &Ws[cid * 8]);
    }
    __syncthreads();
    #pragma unroll
    for (int ks = 0; ks < 2; ++ks) {
      bf16x8 af[4], bf[NJ];
      #pragma unroll
      for (int i = 0; i < 4; ++i)
        af[i] = *(const bf16x8*)&As[(wr * 64 + i * 16 + lr) * 64 + ks * 32 + lg * 8];
      #pragma unroll
      for (int j = 0; j < NJ; ++j)
        bf[j] = *(const bf16x8*)&Ws[(wc * (BN / 2) + j * 16 + lr) * 64 + ks * 32 + lg * 8];
      #pragma unroll
      for (int mi = 0; mi < 4; ++mi)
        #pragma unroll
        for (int nj = 0; nj < NJ; ++nj)
          acc[mi][nj] = __builtin_amdgcn_mfma_f32_16x16x32_bf16(af[mi], bf[nj], acc[mi][nj], 0, 0, 0);
    }
    __syncthreads();
  }
  // ---- fused epilogue ----
  #pragma unroll
  for (int nj = 0; nj < NJ; ++nj) {
    const int cn = bn + wc * (BN / 2) + nj * 16 + lr;
    const float bv = (MODE == 0) ? bias[cn] : 0.0f;
    #pragma unroll
    for (int mi = 0; mi < 4; ++mi) {
      const int rm = bm + wr * 64 + mi * 16 + lg * 4;
      const int bb = rm >> 11, tl = rm & (T_ - 1);
      if (MODE == 0) {
        #pragma unroll
        for (int r = 0; r < 4; ++r)
          Cf[(size_t)(rm + r) * N + cn] = acc[mi][nj][r] + bv;
      } else {  // MODE 3
        if (cn >= 2560) {
          // V: direct transposed store (4 consecutive t at fixed d)
          const int c = cn - 2560, gg = c >> 7, d = c & 127;
          ushort4 ov;
          ov.x = f2bf(acc[mi][nj][0]); ov.y = f2bf(acc[mi][nj][1]);
          ov.z = f2bf(acc[mi][nj][2]); ov.w = f2bf(acc[mi][nj][3]);
          *(ushort4*)&O2[(((size_t)(bb * NKV + gg)) * HD + d) * T_ + tl] = ov;
        } else {
          const int d = cn & 127;
          #pragma unroll
          for (int r = 0; r < 4; ++r) {
            const int t = tl + r;
            const float v = acc[mi][nj][r];
            const float2 cs = *(const float2*)&rf[t * HD + (d & ~1)];
            const float p = __shfl_xor(v, 1);
            float o = (cn & 1) ? (p * cs.y + v * cs.x) : (v * cs.x - p * cs.y);
            if (cn < 2048) {  // Q
              o *= 0.08838834764831845f;  // 1/sqrt(128)
              O1[(((size_t)(bb * NH + (cn >> 7))) * T_ + t) * HD + d] = f2bf(o);
            } else {          // K
              const int c = cn - 2048;
              O3[(((size_t)(bb * NKV + (c >> 7))) * T_ + t) * HD + d] = f2bf(o);
            }
          }
        }
      }
    }
  }
}

// MFMA flash attention — r24: single-buffered K/V (32KB LDS) with
// __launch_bounds__(512, 4). The r20 attempt was confounded by a forced
// spill ((512,8) -> 64-VGPR budget -> acc spill, 536MB scratch). With the
// 4-wave bound the compiler keeps ~56 VGPR; runtime occupancy = min(regs
// 8 waves/SIMD, LDS 5 blocks) -> 4 blocks/CU vs r14 dbuf's 2. Hypothesis
// (from r10 GEMM evidence): cross-block TLP > intra-block dbuf. All else
// byte-identical to the 235.3us-locked config: QBLK=128, KVBLK=64, 8 waves,
// swapped QK^T, bpermute P-remap, XOR-swizzle both-sides, no setprio,
// T13 defer-max. If this regresses, next round reverts to r23 lock-in.
__global__ __launch_bounds__(512, 4)
void flash_attn(const ushort* __restrict__ Qb, const ushort* __restrict__ Kb,
                const ushort* __restrict__ Vt, ushort* __restrict__ ATb) {
  __shared__ __align__(16) ushort Ks[64 * 128];   // [kv s][d], swizzled
  __shared__ __align__(16) ushort Vs[128 * 64];   // [d][kv s], swizzled

  // Makespan-balanced flat grid: pair block f (first dispatch round) with
  // f+256 (second round) so their strip lengths are complementary.
  const int f = blockIdx.x;
  const int second = f >> 8;
  const int fb = f & 255;
  const int bxl = fb & 15;
  const int bh = (fb >> 4) + (second << 4);   // 0..31
  const int qstrip = second ? bxl : (15 - bxl);
  const int q0 = qstrip * 128;

  const int b = bh >> 4, h = bh & 15, g = h & (NKV - 1);
  const int tid = threadIdx.x;
  const int wid = tid >> 6;
  const int lane = tid & 63;
  const int lg = lane >> 4;
  const int qi = lane & 15;
  const int qrow = q0 + wid * 16 + qi;
  const int swz = (qi & 7) << 4;   // read-side XOR

  const ushort* Qw = Qb + (((size_t)(b * NH + h)) * T_ + qrow) * HD;
  bf16x8 qf[4];
  #pragma unroll
  for (int dsl = 0; dsl < 4; ++dsl)
    qf[dsl] = *(const bf16x8*)(Qw + dsl * 32 + lg * 8);

  const ushort* Kbase = Kb + ((size_t)(b * NKV + g)) * T_ * HD;
  const ushort* Vbase = Vt + ((size_t)(b * NKV + g)) * HD * T_;

  float m = -3.0e38f, l = 0.f;
  f32x4 oacc[8];
  #pragma unroll
  for (int i = 0; i < 8; ++i) oacc[i] = f32x4{0.f, 0.f, 0.f, 0.f};

  const int nkv = 2 * qstrip + 2;

  auto stage = [&](int sblk) {
    #pragma unroll
    for (int it = 0; it < 2; ++it) {
      const int c = it * 512 + tid;
      {  // K
        const int r = c >> 4, o = (c & 15) * 16;
        gload16(Kbase + (size_t)(sblk + r) * HD + ((o ^ ((r & 7) << 4)) >> 1),
                &Ks[c * 8]);
      }
      {  // V
        const int d = c >> 3, o = (c & 7) * 16;
        gload16(Vbase + (size_t)d * T_ + sblk + ((o ^ ((d & 7) << 4)) >> 1),
                &Vs[c * 8]);
      }
    }
  };

  auto compute = [&](int kv) {
    const int sblk = kv * 64;
    f32x4 sacc[4];
    #pragma unroll
    for (int st = 0; st < 4; ++st) sacc[st] = f32x4{0.f, 0.f, 0.f, 0.f};
    #pragma unroll
    for (int st = 0; st < 4; ++st) {
      const ushort* kr = &Ks[(st * 16 + qi) * 128];
      #pragma unroll
      for (int dsl = 0; dsl < 4; ++dsl) {
        bf16x8 kf = *(const bf16x8*)(kr + (((dsl * 64 + lg * 16) ^ swz) >> 1));
        sacc[st] = __builtin_amdgcn_mfma_f32_16x16x32_bf16(kf, qf[dsl], sacc[st], 0, 0, 0);
      }
    }
    float sc[16];
    #pragma unroll
    for (int st = 0; st < 4; ++st)
      #pragma unroll
      for (int r = 0; r < 4; ++r) sc[st * 4 + r] = sacc[st][r];
    if (kv >= nkv - 2) {  // only the last two tiles can touch the diagonal
      #pragma unroll
      for (int st = 0; st < 4; ++st)
        #pragma unroll
        for (int r = 0; r < 4; ++r) {
          const int s = sblk + st * 16 + lg * 4 + r;
          if (s > qrow) sc[st * 4 + r] = -3.0e38f;
        }
    }
    float mt = sc[0];
    #pragma unroll
    for (int i = 1; i < 16; ++i) mt = fmaxf(mt, sc[i]);
    mt = fmaxf(mt, __shfl_xor(mt, 16));
    mt = fmaxf(mt, __shfl_xor(mt, 32));
    // T13 defer-max: only rescale when the tile max grew by > 8.
    if (!__all(mt - m <= 8.0f)) {
      const float mn = fmaxf(m, mt);
      const float alpha = __expf(m - mn);
      l *= alpha;
      #pragma unroll
      for (int i = 0; i < 8; ++i) oacc[i] *= alpha;
      m = mn;
    }
    float ps = 0.f;
    #pragma unroll
    for (int i = 0; i < 16; ++i) { sc[i] = __expf(sc[i] - m); ps += sc[i]; }
    ps += __shfl_xor(ps, 16);
    ps += __shfl_xor(ps, 32);
    l += ps;
    uint32_t wtw[4][2];
    #pragma unroll
    for (int t = 0; t < 4; ++t) {
      wtw[t][0] = pack_bf(sc[4 * t + 0], sc[4 * t + 1]);
      wtw[t][1] = pack_bf(sc[4 * t + 2], sc[4 * t + 3]);
    }
    bf16x8 pfrag[2];
    #pragma unroll
    for (int ss = 0; ss < 2; ++ss) {
      int w[4];
      #pragma unroll
      for (int v = 0; v < 4; ++v) {
        const int addr = ((2 * (lg & 1) + (v >> 1)) * 16 + qi) * 4;
        const int r0 = __builtin_amdgcn_ds_bpermute(addr, (int)wtw[2 * ss][v & 1]);
        const int r1 = __builtin_amdgcn_ds_bpermute(addr, (int)wtw[2 * ss + 1][v & 1]);
        w[v] = (lg & 2) ? r1 : r0;
      }
      i32x4 tmp = {w[0], w[1], w[2], w[3]};
      pfrag[ss] = __builtin_bit_cast(bf16x8, tmp);
    }
    #pragma unroll
    for (int dt = 0; dt < 8; ++dt) {
      const ushort* vr = &Vs[(dt * 16 + qi) * 64];
      const bf16x8 v0 = *(const bf16x8*)(vr + (((lg * 16) ^ swz) >> 1));
      const bf16x8 v1 = *(const bf16x8*)(vr + (((64 + lg * 16) ^ swz) >> 1));
      oacc[dt] = __builtin_amdgcn_mfma_f32_16x16x32_bf16(v0, pfrag[0], oacc[dt], 0, 0, 0);
      oacc[dt] = __builtin_amdgcn_mfma_f32_16x16x32_bf16(v1, pfrag[1], oacc[dt], 0, 0, 0);
    }
  };

  // ---- single-buffer main loop (1-phase; cross-block TLP hides staging) ----
  for (int kv = 0; kv < nkv; ++kv) {
    stage(kv * 64);
    __syncthreads();        // staging complete (vmcnt drain)
    compute(kv);
    if (kv != nkv - 1) __syncthreads();  // protect LDS reuse
  }

  const float inv = 1.0f / l;
  ushort* orow = ATb + ((size_t)(b * T_) + qrow) * C_ + h * HD;
  #pragma unroll
  for (int dt = 0; dt < 8; ++dt) {
    f32x4 o = oacc[dt] * inv;
    ushort4 ob;
    ob.x = f2bf(o[0]); ob.y = f2bf(o[1]); ob.z = f2bf(o[2]); ob.w = f2bf(o[3]);
    *(ushort4*)(orow + dt * 16 + lg * 4) = ob;
  }
}

extern "C" void kernel_launch(void* const* d_in, const int* in_sizes, int n_in,
                              void* d_out, int out_size, void* d_ws, size_t ws_size,
                              hipStream_t stream) {
  const float* x   = (const float*)d_in[0];
  const float* rf  = (const float*)d_in[1];
  const float* wq  = (const float*)d_in[2];
  const float* wkv = (const float*)d_in[3];
  const float* wo  = (const float*)d_in[4];
  const float* bo  = (const float*)d_in[5];
  float* out = (float*)d_out;

  uint8_t* w = (uint8_t*)d_ws;
  ushort* ATb   = (ushort*)w;  w += (size_t)4096 * 2048 * 2;   // 16 MB
  ushort* Qb    = (ushort*)w;  w += (size_t)4096 * 2048 * 2;   // 16 MB
  ushort* Kb    = (ushort*)w;  w += (size_t)4096 * 512 * 2;    //  4 MB
  ushort* Vt    = (ushort*)w;  w += (size_t)4096 * 512 * 2;    //  4 MB
  ushort* xb    = (ushort*)w;  w += (size_t)4096 * 2048 * 2;   // 16 MB
  ushort* wqkvb = (ushort*)w;  w += (size_t)3072 * 2048 * 2;   // 12 MB
  ushort* wob   = (ushort*)w;  w += (size_t)2048 * 2048 * 2;   //  8 MB

  dim3 blk(256);
  // all input casts in one dispatch (wq+wkv stacked into wqkvb)
  cast_all<<<dim3(2304), blk, 0, stream>>>(x, wq, wkv, wo, xb, wqkvb, wob);

  // combined QKV projection: Q+RoPE -> Qb, K+RoPE -> Kb, V -> Vt (transposed)
  gemm_mfma<3, 64><<<dim3(48, 32), blk, 0, stream>>>(xb, wqkvb, nullptr, nullptr,
                                                     Qb, Vt, Kb, rf, 4096, 3072, 2048);
  flash_attn<<<dim3(512), dim3(512), 0, stream>>>(Qb, Kb, Vt, ATb);
  // Output projection + bias -> out (f32); BN=64 (r19: BN=32 regressed)
  gemm_mfma<0, 64><<<dim3(32, 32), blk, 0, stream>>>(ATb, wob, bo, out,
                                                     nullptr, nullptr, nullptr, nullptr, 4096, 2048, 2048);
}

// Round 25
// 205.342 us; speedup vs baseline: 1.1731x; 1.1731x over previous
//
#include <hip/hip_runtime.h>
#include <hip/hip_bf16.h>
#include <stdint.h>

#define B_ 2
#define T_ 2048
#define C_ 2048
#define NH 16
#define NKV 4
#define HD 128

typedef __attribute__((ext_vector_type(4))) float f32x4;
typedef __attribute__((ext_vector_type(8))) short bf16x8;
typedef __attribute__((ext_vector_type(4))) int i32x4;

static __device__ __forceinline__ ushort f2bf(float f) {
  return __bfloat16_as_ushort(__float2bfloat16(f));
}
static __device__ __forceinline__ uint32_t pack_bf(float a, float b) {
  return (uint32_t)f2bf(a) | ((uint32_t)f2bf(b) << 16);
}

typedef __attribute__((address_space(1))) const void g1void;
typedef __attribute__((address_space(3))) void l3void;
static __device__ __forceinline__ void gload16(const void* g, void* l) {
  // async global->LDS, 16B per lane; LDS dest = wave-uniform base + lane*16
  __builtin_amdgcn_global_load_lds((g1void*)g, (l3void*)l, 16, 0, 0);
}

// ---- all f32 -> bf16 casts in ONE dispatch (segmented grid) ----
// segments: x (1024 blocks), wq (512), wkv (256), wo (512) = 2304 blocks.
__global__ __launch_bounds__(256)
void cast_all(const float* __restrict__ x, const float* __restrict__ wq,
              const float* __restrict__ wkv, const float* __restrict__ wo,
              ushort* __restrict__ xb, ushort* __restrict__ wqkvb,
              ushort* __restrict__ wob) {
  const int bid = blockIdx.x;
  const float* src; ushort* dst; int n4, b0, nblk;
  if (bid < 1024)      { src = x;   dst = xb;    n4 = 2097152; b0 = 0;    nblk = 1024; }
  else if (bid < 1536) { src = wq;  dst = wqkvb; n4 = 1048576; b0 = 1024; nblk = 512; }
  else if (bid < 1792) { src = wkv; dst = wqkvb + (size_t)2048 * 2048;
                         n4 = 524288;  b0 = 1536; nblk = 256; }
  else                 { src = wo;  dst = wob;   n4 = 1048576; b0 = 1792; nblk = 512; }
  for (int i = (bid - b0) * 256 + threadIdx.x; i < n4; i += nblk * 256) {
    float4 v = ((const float4*)src)[i];
    ushort4 o;
    o.x = f2bf(v.x); o.y = f2bf(v.y); o.z = f2bf(v.z); o.w = f2bf(v.w);
    ((ushort4*)dst)[i] = o;
  }
}

// ---- bf16 MFMA GEMM: 128x64 tile (BN=64 measured optimum, r19). 256 thr =
// 4 waves (2x2), wave 64x32 (acc 4x2). 1-phase (r10: dbuf loses cross-block
// TLP). r25: T2-style XOR swizzle on As/Ws (rule #21 both-sides: pre-swizzled
// GLOBAL source chunk + same XOR on ds_read). Counter evidence: 2.83e7
// bank-conflict cycles/dispatch from 16-way conflicts on 128B-stride frag
// reads; swizzle -> 2-way (free, m136). Chunk index within row (8 elems)
// XOR'd with row&7 — bijective per row.
// MODE 0: C = A@W^T + bias, f32 out (O-projection).
// MODE 3: combined QKV projection, N=3072 (W = [wq; wkv] stacked):
//   cn < 2048: RoPE*scale -> Qb;  cn < 2560: RoPE -> Kb;
//   else: transpose-store -> Vt[b][g][d][t] (r=0..3 = 4 consecutive t).
// RoPE pair element via __shfl_xor(v,1): lane parity == column parity.
template<int MODE, int BN>
__global__ __launch_bounds__(256)
void gemm_mfma(const ushort* __restrict__ A, const ushort* __restrict__ W,
               const float* __restrict__ bias, float* __restrict__ Cf,
               ushort* __restrict__ O1, ushort* __restrict__ O2,
               ushort* __restrict__ O3,
               const float* __restrict__ rf, int M, int N, int K) {
  constexpr int NJ = BN / 32;
  __shared__ __align__(16) ushort As[128 * 64];
  __shared__ __align__(16) ushort Ws[BN * 64];
  const int tid = threadIdx.x;
  const int lane = tid & 63, wid = tid >> 6;
  const int wr = wid >> 1, wc = wid & 1;       // wave grid 2x2 (rows 64, cols BN/2)
  const int lr = lane & 15, lg = lane >> 4;
  const int bm = blockIdx.y * 128, bn = blockIdx.x * BN;
  const int rsw = (lr & 7) << 3;               // read-side XOR (elements)

  f32x4 acc[4][NJ];
  #pragma unroll
  for (int mi = 0; mi < 4; ++mi)
    #pragma unroll
    for (int nj = 0; nj < NJ; ++nj) acc[mi][nj] = f32x4{0.f, 0.f, 0.f, 0.f};

  const ushort* Ab = A + (size_t)bm * K;
  const ushort* Wb = W + (size_t)bn * K;

  for (int k0 = 0; k0 < K; k0 += 64) {
    // stage A 128x64 (1024 x 16B chunks), W BNx64 (BN*8 chunks).
    // Global source column pre-swizzled: cc ^ ((r&7)<<3) (8-elem chunks).
    #pragma unroll
    for (int it = 0; it < 4; ++it) {
      const int cid = it * 256 + tid;
      const int r = cid >> 3, cc = (cid & 7) * 8;
      gload16(Ab + (size_t)r * K + k0 + (cc ^ ((r & 7) << 3)), &As[cid * 8]);
    }
    #pragma unroll
    for (int it = 0; it < NJ; ++it) {
      const int cid = it * 256 + tid;
      const int r = cid >> 3, cc = (cid & 7) * 8;
      gload16(Wb + (size_t)r * K + k0 + (cc ^ ((r & 7) << 3)), &Ws[cid * 8]);
    }
    __syncthreads();
    #pragma unroll
    for (int ks = 0; ks < 2; ++ks) {
      bf16x8 af[4], bf[NJ];
      #pragma unroll
      for (int i = 0; i < 4; ++i)
        af[i] = *(const bf16x8*)&As[(wr * 64 + i * 16 + lr) * 64 + ((ks * 32 + lg * 8) ^ rsw)];
      #pragma unroll
      for (int j = 0; j < NJ; ++j)
        bf[j] = *(const bf16x8*)&Ws[(wc * (BN / 2) + j * 16 + lr) * 64 + ((ks * 32 + lg * 8) ^ rsw)];
      #pragma unroll
      for (int mi = 0; mi < 4; ++mi)
        #pragma unroll
        for (int nj = 0; nj < NJ; ++nj)
          acc[mi][nj] = __builtin_amdgcn_mfma_f32_16x16x32_bf16(af[mi], bf[nj], acc[mi][nj], 0, 0, 0);
    }
    __syncthreads();
  }
  // ---- fused epilogue ----
  #pragma unroll
  for (int nj = 0; nj < NJ; ++nj) {
    const int cn = bn + wc * (BN / 2) + nj * 16 + lr;
    const float bv = (MODE == 0) ? bias[cn] : 0.0f;
    #pragma unroll
    for (int mi = 0; mi < 4; ++mi) {
      const int rm = bm + wr * 64 + mi * 16 + lg * 4;
      const int bb = rm >> 11, tl = rm & (T_ - 1);
      if (MODE == 0) {
        #pragma unroll
        for (int r = 0; r < 4; ++r)
          Cf[(size_t)(rm + r) * N + cn] = acc[mi][nj][r] + bv;
      } else {  // MODE 3
        if (cn >= 2560) {
          // V: direct transposed store (4 consecutive t at fixed d)
          const int c = cn - 2560, gg = c >> 7, d = c & 127;
          ushort4 ov;
          ov.x = f2bf(acc[mi][nj][0]); ov.y = f2bf(acc[mi][nj][1]);
          ov.z = f2bf(acc[mi][nj][2]); ov.w = f2bf(acc[mi][nj][3]);
          *(ushort4*)&O2[(((size_t)(bb * NKV + gg)) * HD + d) * T_ + tl] = ov;
        } else {
          const int d = cn & 127;
          #pragma unroll
          for (int r = 0; r < 4; ++r) {
            const int t = tl + r;
            const float v = acc[mi][nj][r];
            const float2 cs = *(const float2*)&rf[t * HD + (d & ~1)];
            const float p = __shfl_xor(v, 1);
            float o = (cn & 1) ? (p * cs.y + v * cs.x) : (v * cs.x - p * cs.y);
            if (cn < 2048) {  // Q
              o *= 0.08838834764831845f;  // 1/sqrt(128)
              O1[(((size_t)(bb * NH + (cn >> 7))) * T_ + t) * HD + d] = f2bf(o);
            } else {          // K
              const int c = cn - 2048;
              O3[(((size_t)(bb * NKV + (c >> 7))) * T_ + t) * HD + d] = f2bf(o);
            }
          }
        }
      }
    }
  }
}

// MFMA flash attention — EXACT r14/r23 config (measured 80us; r24 single-
// buffer was +5us, refuted). LDS-staged + double-buffered K/V shared by 8
// waves. QBLK=128, KVBLK=64. Swapped QK^T, bpermute P-remap (hardware-
// verified round 5). K/V tiles XOR-swizzled both-sides (rule #21).
// No setprio (r9/r10 A/B). T13 defer-max kept.
__global__ __launch_bounds__(512, 4)
void flash_attn(const ushort* __restrict__ Qb, const ushort* __restrict__ Kb,
                const ushort* __restrict__ Vt, ushort* __restrict__ ATb) {
  __shared__ __align__(16) ushort Ks[2][64 * 128];   // [kv s][d], swizzled
  __shared__ __align__(16) ushort Vs[2][128 * 64];   // [d][kv s], swizzled

  // Makespan-balanced flat grid: pair block f (first dispatch round) with
  // f+256 (second round) so their strip lengths are complementary.
  const int f = blockIdx.x;
  const int second = f >> 8;
  const int fb = f & 255;
  const int bxl = fb & 15;
  const int bh = (fb >> 4) + (second << 4);   // 0..31
  const int qstrip = second ? bxl : (15 - bxl);
  const int q0 = qstrip * 128;

  const int b = bh >> 4, h = bh & 15, g = h & (NKV - 1);
  const int tid = threadIdx.x;
  const int wid = tid >> 6;
  const int lane = tid & 63;
  const int lg = lane >> 4;
  const int qi = lane & 15;
  const int qrow = q0 + wid * 16 + qi;
  const int swz = (qi & 7) << 4;   // read-side XOR

  const ushort* Qw = Qb + (((size_t)(b * NH + h)) * T_ + qrow) * HD;
  bf16x8 qf[4];
  #pragma unroll
  for (int dsl = 0; dsl < 4; ++dsl)
    qf[dsl] = *(const bf16x8*)(Qw + dsl * 32 + lg * 8);

  const ushort* Kbase = Kb + ((size_t)(b * NKV + g)) * T_ * HD;
  const ushort* Vbase = Vt + ((size_t)(b * NKV + g)) * HD * T_;

  float m = -3.0e38f, l = 0.f;
  f32x4 oacc[8];
  #pragma unroll
  for (int i = 0; i < 8; ++i) oacc[i] = f32x4{0.f, 0.f, 0.f, 0.f};

  const int nkv = 2 * qstrip + 2;

  auto stage = [&](int buf, int sblk) {
    #pragma unroll
    for (int it = 0; it < 2; ++it) {
      const int c = it * 512 + tid;
      {  // K
        const int r = c >> 4, o = (c & 15) * 16;
        gload16(Kbase + (size_t)(sblk + r) * HD + ((o ^ ((r & 7) << 4)) >> 1),
                &Ks[buf][c * 8]);
      }
      {  // V
        const int d = c >> 3, o = (c & 7) * 16;
        gload16(Vbase + (size_t)d * T_ + sblk + ((o ^ ((d & 7) << 4)) >> 1),
                &Vs[buf][c * 8]);
      }
    }
  };

  auto compute = [&](int buf, int kv) {
    const int sblk = kv * 64;
    f32x4 sacc[4];
    #pragma unroll
    for (int st = 0; st < 4; ++st) sacc[st] = f32x4{0.f, 0.f, 0.f, 0.f};
    #pragma unroll
    for (int st = 0; st < 4; ++st) {
      const ushort* kr = &Ks[buf][(st * 16 + qi) * 128];
      #pragma unroll
      for (int dsl = 0; dsl < 4; ++dsl) {
        bf16x8 kf = *(const bf16x8*)(kr + (((dsl * 64 + lg * 16) ^ swz) >> 1));
        sacc[st] = __builtin_amdgcn_mfma_f32_16x16x32_bf16(kf, qf[dsl], sacc[st], 0, 0, 0);
      }
    }
    float sc[16];
    #pragma unroll
    for (int st = 0; st < 4; ++st)
      #pragma unroll
      for (int r = 0; r < 4; ++r) sc[st * 4 + r] = sacc[st][r];
    if (kv >= nkv - 2) {  // only the last two tiles can touch the diagonal
      #pragma unroll
      for (int st = 0; st < 4; ++st)
        #pragma unroll
        for (int r = 0; r < 4; ++r) {
          const int s = sblk + st * 16 + lg * 4 + r;
          if (s > qrow) sc[st * 4 + r] = -3.0e38f;
        }
    }
    float mt = sc[0];
    #pragma unroll
    for (int i = 1; i < 16; ++i) mt = fmaxf(mt, sc[i]);
    mt = fmaxf(mt, __shfl_xor(mt, 16));
    mt = fmaxf(mt, __shfl_xor(mt, 32));
    // T13 defer-max: only rescale when the tile max grew by > 8.
    if (!__all(mt - m <= 8.0f)) {
      const float mn = fmaxf(m, mt);
      const float alpha = __expf(m - mn);
      l *= alpha;
      #pragma unroll
      for (int i = 0; i < 8; ++i) oacc[i] *= alpha;
      m = mn;
    }
    float ps = 0.f;
    #pragma unroll
    for (int i = 0; i < 16; ++i) { sc[i] = __expf(sc[i] - m); ps += sc[i]; }
    ps += __shfl_xor(ps, 16);
    ps += __shfl_xor(ps, 32);
    l += ps;
    uint32_t wtw[4][2];
    #pragma unroll
    for (int t = 0; t < 4; ++t) {
      wtw[t][0] = pack_bf(sc[4 * t + 0], sc[4 * t + 1]);
      wtw[t][1] = pack_bf(sc[4 * t + 2], sc[4 * t + 3]);
    }
    bf16x8 pfrag[2];
    #pragma unroll
    for (int ss = 0; ss < 2; ++ss) {
      int w[4];
      #pragma unroll
      for (int v = 0; v < 4; ++v) {
        const int addr = ((2 * (lg & 1) + (v >> 1)) * 16 + qi) * 4;
        const int r0 = __builtin_amdgcn_ds_bpermute(addr, (int)wtw[2 * ss][v & 1]);
        const int r1 = __builtin_amdgcn_ds_bpermute(addr, (int)wtw[2 * ss + 1][v & 1]);
        w[v] = (lg & 2) ? r1 : r0;
      }
      i32x4 tmp = {w[0], w[1], w[2], w[3]};
      pfrag[ss] = __builtin_bit_cast(bf16x8, tmp);
    }
    #pragma unroll
    for (int dt = 0; dt < 8; ++dt) {
      const ushort* vr = &Vs[buf][(dt * 16 + qi) * 64];
      const bf16x8 v0 = *(const bf16x8*)(vr + (((lg * 16) ^ swz) >> 1));
      const bf16x8 v1 = *(const bf16x8*)(vr + (((64 + lg * 16) ^ swz) >> 1));
      oacc[dt] = __builtin_amdgcn_mfma_f32_16x16x32_bf16(v0, pfrag[0], oacc[dt], 0, 0, 0);
      oacc[dt] = __builtin_amdgcn_mfma_f32_16x16x32_bf16(v1, pfrag[1], oacc[dt], 0, 0, 0);
    }
  };

  stage(0, 0);
  __syncthreads();
  for (int kv = 0; kv < nkv - 1; ++kv) {
    stage((kv + 1) & 1, (kv + 1) * 64);  // prefetch next tile
    compute(kv & 1, kv);                 // compute current
    __syncthreads();                     // drain prefetch + protect reuse
  }
  compute((nkv - 1) & 1, nkv - 1);

  const float inv = 1.0f / l;
  ushort* orow = ATb + ((size_t)(b * T_) + qrow) * C_ + h * HD;
  #pragma unroll
  for (int dt = 0; dt < 8; ++dt) {
    f32x4 o = oacc[dt] * inv;
    ushort4 ob;
    ob.x = f2bf(o[0]); ob.y = f2bf(o[1]); ob.z = f2bf(o[2]); ob.w = f2bf(o[3]);
    *(ushort4*)(orow + dt * 16 + lg * 4) = ob;
  }
}

extern "C" void kernel_launch(void* const* d_in, const int* in_sizes, int n_in,
                              void* d_out, int out_size, void* d_ws, size_t ws_size,
                              hipStream_t stream) {
  const float* x   = (const float*)d_in[0];
  const float* rf  = (const float*)d_in[1];
  const float* wq  = (const float*)d_in[2];
  const float* wkv = (const float*)d_in[3];
  const float* wo  = (const float*)d_in[4];
  const float* bo  = (const float*)d_in[5];
  float* out = (float*)d_out;

  uint8_t* w = (uint8_t*)d_ws;
  ushort* ATb   = (ushort*)w;  w += (size_t)4096 * 2048 * 2;   // 16 MB
  ushort* Qb    = (ushort*)w;  w += (size_t)4096 * 2048 * 2;   // 16 MB
  ushort* Kb    = (ushort*)w;  w += (size_t)4096 * 512 * 2;    //  4 MB
  ushort* Vt    = (ushort*)w;  w += (size_t)4096 * 512 * 2;    //  4 MB
  ushort* xb    = (ushort*)w;  w += (size_t)4096 * 2048 * 2;   // 16 MB
  ushort* wqkvb = (ushort*)w;  w += (size_t)3072 * 2048 * 2;   // 12 MB
  ushort* wob   = (ushort*)w;  w += (size_t)2048 * 2048 * 2;   //  8 MB

  dim3 blk(256);
  // all input casts in one dispatch (wq+wkv stacked into wqkvb)
  cast_all<<<dim3(2304), blk, 0, stream>>>(x, wq, wkv, wo, xb, wqkvb, wob);

  // combined QKV projection: Q+RoPE -> Qb, K+RoPE -> Kb, V -> Vt (transposed)
  gemm_mfma<3, 64><<<dim3(48, 32), blk, 0, stream>>>(xb, wqkvb, nullptr, nullptr,
                                                     Qb, Vt, Kb, rf, 4096, 3072, 2048);
  flash_attn<<<dim3(512), dim3(512), 0, stream>>>(Qb, Kb, Vt, ATb);
  // Output projection + bias -> out (f32); BN=64 (r19: BN=32 regressed)
  gemm_mfma<0, 64><<<dim3(32, 32), blk, 0, stream>>>(ATb, wob, bo, out,
                                                     nullptr, nullptr, nullptr, nullptr, 4096, 2048, 2048);
}